// Round 6
// baseline (201.245 us; speedup 1.0000x reference)
//
#include <hip/hip_runtime.h>
#include <hip/hip_bf16.h>
#include <hip/hip_cooperative_groups.h>

namespace cg = cooperative_groups;

#define EPS 1e-6f

typedef float  f32x4  __attribute__((ext_vector_type(4)));
typedef __bf16 bf16x8 __attribute__((ext_vector_type(8)));

// ---------- helpers ----------
static __device__ __forceinline__ unsigned short f2bf(float f) {
    unsigned int x = __float_as_uint(f);
    unsigned int r = (x + 0x7FFFu + ((x >> 16) & 1u)) >> 16;   // RNE
    return (unsigned short)r;
}

// ---------- kernel 1: row stats (fp32) + bf16 conversion, both matrices ----------
__global__ __launch_bounds__(256) void prep_kernel(
    const float* __restrict__ protos, const float* __restrict__ querys,
    unsigned short* __restrict__ pb, unsigned short* __restrict__ qb,
    float* __restrict__ p_sq, float* __restrict__ p_sum,
    float* __restrict__ q_sq, float* __restrict__ q_sum)
{
    const int b   = blockIdx.x;
    const int tid = threadIdx.x;
    const float* src; unsigned short* dst; float* rsq; float* rsum;
    if (b < 1024) {
        src = protos + (size_t)b * 1024; dst = pb + (size_t)b * 1024;
        rsq = p_sq + b; rsum = p_sum + b;
    } else {
        const int r = b - 1024;
        src = querys + (size_t)r * 1024; dst = qb + (size_t)r * 1024;
        rsq = q_sq + r; rsum = q_sum + r;
    }

    const float4 v = reinterpret_cast<const float4*>(src)[tid];
    float s  = v.x + v.y + v.z + v.w;
    float ss = v.x * v.x + v.y * v.y + v.z * v.z + v.w * v.w;

    ushort4 o;
    o.x = f2bf(v.x); o.y = f2bf(v.y); o.z = f2bf(v.z); o.w = f2bf(v.w);
    reinterpret_cast<ushort4*>(dst)[tid] = o;

    #pragma unroll
    for (int m = 32; m >= 1; m >>= 1) {
        s  += __shfl_xor(s, m, 64);
        ss += __shfl_xor(ss, m, 64);
    }
    __shared__ float red[8];
    const int wave = tid >> 6;
    if ((tid & 63) == 0) { red[wave] = s; red[4 + wave] = ss; }
    __syncthreads();
    if (tid == 0) {
        *rsum = red[0] + red[1] + red[2] + red[3];
        *rsq  = red[4] + red[5] + red[6] + red[7];
    }
}

// ---------- kernel 2: cooperative GEMM + softmax, e kept in registers across grid sync ----------
// Phase A: proven R1/R4 128x128 gemm core + dist/exp epilogue -> acc holds e; atomics for row stats.
// grid.sync()
// Phase B: normalized f32 post written directly from registers; col-block 0 writes c/h.
// grid = 64 x 8 = 512 blocks = 2 blocks/CU (co-residency exact), 256 threads (4 waves).
__global__ __launch_bounds__(256, 2) void coop_kernel(
    const unsigned short* __restrict__ qb,   // [8192][1024] bf16 bits
    const unsigned short* __restrict__ pb,   // [1024][1024] bf16 bits
    const float* __restrict__ q_sq, const float* __restrict__ q_sum,
    const float* __restrict__ p_sq, const float* __restrict__ p_sum,
    float* __restrict__ row_s, float* __restrict__ row_t,
    unsigned int* __restrict__ row_m,
    float* __restrict__ post, float* __restrict__ c_out, float* __restrict__ h_out)
{
    __shared__ unsigned short As[128 * 32];
    __shared__ unsigned short Bs[128 * 32];

    const int tid  = threadIdx.x;
    const int lane = tid & 63;
    const int wave = tid >> 6;
    const int wr = wave >> 1, wc = wave & 1;
    const int l15 = lane & 15;
    const int l4  = lane >> 4;
    const int br = blockIdx.x, bc = blockIdx.y;

    f32x4 acc[4][4];
    #pragma unroll
    for (int m = 0; m < 4; ++m)
        #pragma unroll
        for (int n = 0; n < 4; ++n)
            acc[m][n] = (f32x4)0.0f;

    const size_t qbase = (size_t)(br * 128) * 1024;
    const size_t pbase = (size_t)(bc * 128) * 1024;
    const int c0 = tid, c1 = tid + 256;     // 16B chunks: row=c>>2, col8=(c&3)*8

    for (int kk = 0; kk < 1024; kk += 32) {
        __syncthreads();
        {
            const unsigned short* gq0 = qb + qbase + (size_t)(c0 >> 2) * 1024 + kk + (c0 & 3) * 8;
            const unsigned short* gq1 = qb + qbase + (size_t)(c1 >> 2) * 1024 + kk + (c1 & 3) * 8;
            const unsigned short* gp0 = pb + pbase + (size_t)(c0 >> 2) * 1024 + kk + (c0 & 3) * 8;
            const unsigned short* gp1 = pb + pbase + (size_t)(c1 >> 2) * 1024 + kk + (c1 & 3) * 8;
            __builtin_amdgcn_global_load_lds((const __attribute__((address_space(1))) void*)gq0,
                                             (__attribute__((address_space(3))) void*)(&As[c0 * 8]), 16, 0, 0);
            __builtin_amdgcn_global_load_lds((const __attribute__((address_space(1))) void*)gq1,
                                             (__attribute__((address_space(3))) void*)(&As[c1 * 8]), 16, 0, 0);
            __builtin_amdgcn_global_load_lds((const __attribute__((address_space(1))) void*)gp0,
                                             (__attribute__((address_space(3))) void*)(&Bs[c0 * 8]), 16, 0, 0);
            __builtin_amdgcn_global_load_lds((const __attribute__((address_space(1))) void*)gp1,
                                             (__attribute__((address_space(3))) void*)(&Bs[c1 * 8]), 16, 0, 0);
        }
        __syncthreads();

        bf16x8 a[4], b[4];
        #pragma unroll
        for (int m = 0; m < 4; ++m)
            a[m] = *reinterpret_cast<const bf16x8*>(&As[(wr * 64 + m * 16 + l15) * 32 + l4 * 8]);
        #pragma unroll
        for (int n = 0; n < 4; ++n)
            b[n] = *reinterpret_cast<const bf16x8*>(&Bs[(wc * 64 + n * 16 + l15) * 32 + l4 * 8]);
        #pragma unroll
        for (int m = 0; m < 4; ++m)
            #pragma unroll
            for (int n = 0; n < 4; ++n)
                acc[m][n] = __builtin_amdgcn_mfma_f32_16x16x32_bf16(a[m], b[n], acc[m][n], 0, 0, 0);
    }

    // ---- epilogue: dist -> e = exp(-dist) in-register; per-row partial stats ----
    const int row0 = br * 128 + wr * 64;   // + m*16 + l4*4 + r
    const int col0 = bc * 128 + wc * 64;   // + n*16 + l15

    float ps[4], pm[4];
    #pragma unroll
    for (int n = 0; n < 4; ++n) {
        const int c = col0 + n * 16 + l15;
        ps[n] = p_sq[c];
        pm[n] = p_sum[c];
    }
    const float dee = 1024.0f * EPS * EPS;

    #pragma unroll
    for (int m = 0; m < 4; ++m) {
        #pragma unroll
        for (int r = 0; r < 4; ++r) {
            const int row = row0 + m * 16 + l4 * 4 + r;
            const float qs = q_sq[row], qm = q_sum[row];
            float se = 0.0f, te = 0.0f, mx = 0.0f;
            #pragma unroll
            for (int n = 0; n < 4; ++n) {
                const float cross = acc[m][n][r];
                const float sq = qs + ps[n] - 2.0f * cross + 2.0f * EPS * (qm - pm[n]) + dee;
                const float dist = sqrtf(fmaxf(sq, 0.0f));
                const float e = __expf(-dist);
                acc[m][n][r] = e;          // keep e in registers for phase B
                se += e;
                te += e * dist;
                mx = fmaxf(mx, e);
            }
            #pragma unroll
            for (int msk = 8; msk >= 1; msk >>= 1) {
                se += __shfl_xor(se, msk, 64);
                te += __shfl_xor(te, msk, 64);
                mx = fmaxf(mx, __shfl_xor(mx, msk, 64));
            }
            if (l15 == 0) {
                atomicAdd(&row_s[row], se);
                atomicAdd(&row_t[row], te);
                atomicMax(&row_m[row], __float_as_uint(mx));
            }
        }
    }

    // ---- grid-wide sync: all row sums complete ----
    cg::this_grid().sync();

    // ---- phase B: normalized store from registers ----
    #pragma unroll
    for (int m = 0; m < 4; ++m) {
        #pragma unroll
        for (int r = 0; r < 4; ++r) {
            const int row = row0 + m * 16 + l4 * 4 + r;
            const float inv = 1.0f / row_s[row];
            #pragma unroll
            for (int n = 0; n < 4; ++n) {
                post[(size_t)row * 1024 + (col0 + n * 16 + l15)] = acc[m][n][r] * inv;
            }
        }
    }

    // c/h: one column-block per row-stripe handles 128 rows
    if (bc == 0 && tid < 128) {
        const int row = br * 128 + tid;
        const float s   = row_s[row];
        const float inv = 1.0f / s;
        c_out[row] = __uint_as_float(row_m[row]) * inv;
        h_out[row] = logf(s) + row_t[row] * inv;   // h = t/s + log s
    }
}

// ---------- launcher ----------
extern "C" void kernel_launch(void* const* d_in, const int* in_sizes, int n_in,
                              void* d_out, int out_size, void* d_ws, size_t ws_size,
                              hipStream_t stream) {
    const float* protos = (const float*)d_in[0];  // [1024,1024]
    const float* querys = (const float*)d_in[1];  // [8192,1024]

    float* out   = (float*)d_out;
    float* post  = out;                            // 8192*1024
    float* c_out = out + (size_t)8192 * 1024;      // 8192
    float* h_out = c_out + 8192;                   // 8192

    char* ws = (char*)d_ws;
    unsigned short* qb = (unsigned short*)ws;  ws += (size_t)8192 * 1024 * 2;
    unsigned short* pb = (unsigned short*)ws;  ws += (size_t)1024 * 1024 * 2;
    float* q_sq  = (float*)ws;  ws += 8192 * 4;
    float* q_sum = (float*)ws;  ws += 8192 * 4;
    float* p_sq  = (float*)ws;  ws += 1024 * 4;
    float* p_sum = (float*)ws;  ws += 1024 * 4;
    float* row_s = (float*)ws;  ws += 8192 * 4;
    float* row_t = (float*)ws;  ws += 8192 * 4;
    unsigned int* row_m = (unsigned int*)ws;  ws += 8192 * 4;

    // zero the atomic accumulators (row_s, row_t, row_m are contiguous)
    (void)hipMemsetAsync(row_s, 0, 3 * 8192 * sizeof(float), stream);

    prep_kernel<<<9216, 256, 0, stream>>>(protos, querys, pb, qb, p_sq, p_sum, q_sq, q_sum);

    void* args[] = { (void*)&qb, (void*)&pb, (void*)&q_sq, (void*)&q_sum,
                     (void*)&p_sq, (void*)&p_sum, (void*)&row_s, (void*)&row_t,
                     (void*)&row_m, (void*)&post, (void*)&c_out, (void*)&h_out };
    (void)hipLaunchCooperativeKernel((const void*)coop_kernel, dim3(64, 8), dim3(256),
                                     args, 0, stream);
}

// Round 7
// 136.758 us; speedup vs baseline: 1.4715x; 1.4715x over previous
//
#include <hip/hip_runtime.h>
#include <hip/hip_bf16.h>

#define EPS 1e-6f

typedef float  f32x4  __attribute__((ext_vector_type(4)));
typedef __bf16 bf16x8 __attribute__((ext_vector_type(8)));

// ---------- helpers ----------
static __device__ __forceinline__ unsigned short f2bf(float f) {
    unsigned int x = __float_as_uint(f);
    unsigned int r = (x + 0x7FFFu + ((x >> 16) & 1u)) >> 16;   // RNE
    return (unsigned short)r;
}
static __device__ __forceinline__ float bf2f(unsigned short u) {
    return __uint_as_float((unsigned int)u << 16);
}

// ---------- kernel 1: row stats (fp32) + bf16 conversion, both matrices ----------
__global__ __launch_bounds__(256) void prep_kernel(
    const float* __restrict__ protos, const float* __restrict__ querys,
    unsigned short* __restrict__ pb, unsigned short* __restrict__ qb,
    float* __restrict__ p_sq, float* __restrict__ p_sum,
    float* __restrict__ q_sq, float* __restrict__ q_sum)
{
    const int b   = blockIdx.x;
    const int tid = threadIdx.x;
    const float* src; unsigned short* dst; float* rsq; float* rsum;
    if (b < 1024) {
        src = protos + (size_t)b * 1024; dst = pb + (size_t)b * 1024;
        rsq = p_sq + b; rsum = p_sum + b;
    } else {
        const int r = b - 1024;
        src = querys + (size_t)r * 1024; dst = qb + (size_t)r * 1024;
        rsq = q_sq + r; rsum = q_sum + r;
    }

    const float4 v = reinterpret_cast<const float4*>(src)[tid];
    float s  = v.x + v.y + v.z + v.w;
    float ss = v.x * v.x + v.y * v.y + v.z * v.z + v.w * v.w;

    ushort4 o;
    o.x = f2bf(v.x); o.y = f2bf(v.y); o.z = f2bf(v.z); o.w = f2bf(v.w);
    reinterpret_cast<ushort4*>(dst)[tid] = o;

    #pragma unroll
    for (int m = 32; m >= 1; m >>= 1) {
        s  += __shfl_xor(s, m, 64);
        ss += __shfl_xor(ss, m, 64);
    }
    __shared__ float red[8];
    const int wave = tid >> 6;
    if ((tid & 63) == 0) { red[wave] = s; red[4 + wave] = ss; }
    __syncthreads();
    if (tid == 0) {
        *rsum = red[0] + red[1] + red[2] + red[3];
        *rsq  = red[4] + red[5] + red[6] + red[7];
    }
}

// ---------- kernel 2: bf16 MFMA GEMM + dist/exp epilogue ----------
// Tile 128(M)x64(N), BK=32, 256 threads = 4 waves (2x2); wave-tile 64x32 (4x2 frags).
// grid = 64x16 = 1024 blocks = 4 blocks/CU (occupancy-driven; VGPR<=128 via launch_bounds).
// LDS bank-conflict fix (rule #21): linear global_load_lds dest + inverse-permuted
// global SOURCE chunk (kp ^= row[1:2]) + matching XOR on ds_read (l4 ^ row[1:2]).
// XCD chunk swizzle: each XCD = 8 row-blocks x 16 col-blocks (P 2MB + Q-panels 2MB = L2).
__global__ __launch_bounds__(256, 4) void gemm_exp_kernel(
    const unsigned short* __restrict__ qb,   // [8192][1024] bf16 bits
    const unsigned short* __restrict__ pb,   // [1024][1024] bf16 bits
    const float* __restrict__ q_sq, const float* __restrict__ q_sum,
    const float* __restrict__ p_sq, const float* __restrict__ p_sum,
    unsigned short* __restrict__ e_out,      // [8192][1024] bf16 un-normalized exp(-dist)
    float* __restrict__ row_s, float* __restrict__ row_t,
    unsigned int* __restrict__ row_m)
{
    __shared__ unsigned short As[128 * 32];  // 8 KiB
    __shared__ unsigned short Bs[64 * 32];   // 4 KiB

    const int tid  = threadIdx.x;
    const int lane = tid & 63;
    const int wave = tid >> 6;
    const int wr = wave >> 1, wc = wave & 1;   // 2x2 waves: M-half, N-half
    const int l15 = lane & 15;
    const int l4  = lane >> 4;

    // XCD-aware bijective remap (1024 blocks, 8 XCDs)
    const int hwid  = blockIdx.x + blockIdx.y * 64;
    const int newid = (hwid & 7) * 128 + (hwid >> 3);
    const int bx = newid >> 4;    // row-block  0..63  (128 rows each)
    const int by = newid & 15;    // col-block  0..15  (64 cols each)

    f32x4 acc[4][2];
    #pragma unroll
    for (int m = 0; m < 4; ++m)
        #pragma unroll
        for (int n = 0; n < 2; ++n)
            acc[m][n] = (f32x4)0.0f;

    const size_t qbase = (size_t)(bx * 128) * 1024;
    const size_t pbase = (size_t)(by * 64) * 1024;

    for (int kk = 0; kk < 1024; kk += 32) {
        __syncthreads();
        {
            // A: 512 chunks of 16B (row = lin>>2), B: 256 chunks. Source chunk index
            // inverse-swizzled: kp = (lin&3) ^ ((lin>>3)&3)  (XOR row bits[1:2]).
            const int la0 = tid,      la1 = tid + 256, lb = tid;
            const int kpa0 = (la0 & 3) ^ ((la0 >> 3) & 3);
            const int kpa1 = (la1 & 3) ^ ((la1 >> 3) & 3);
            const int kpb  = (lb  & 3) ^ ((lb  >> 3) & 3);
            const unsigned short* ga0 = qb + qbase + (size_t)(la0 >> 2) * 1024 + kk + kpa0 * 8;
            const unsigned short* ga1 = qb + qbase + (size_t)(la1 >> 2) * 1024 + kk + kpa1 * 8;
            const unsigned short* gb  = pb + pbase + (size_t)(lb  >> 2) * 1024 + kk + kpb  * 8;
            __builtin_amdgcn_global_load_lds((const __attribute__((address_space(1))) void*)ga0,
                                             (__attribute__((address_space(3))) void*)(&As[la0 * 8]), 16, 0, 0);
            __builtin_amdgcn_global_load_lds((const __attribute__((address_space(1))) void*)ga1,
                                             (__attribute__((address_space(3))) void*)(&As[la1 * 8]), 16, 0, 0);
            __builtin_amdgcn_global_load_lds((const __attribute__((address_space(1))) void*)gb,
                                             (__attribute__((address_space(3))) void*)(&Bs[lb * 8]), 16, 0, 0);
        }
        __syncthreads();

        bf16x8 a[4], b[2];
        #pragma unroll
        for (int m = 0; m < 4; ++m) {
            const int rowA = wr * 64 + m * 16 + l15;
            a[m] = *reinterpret_cast<const bf16x8*>(&As[rowA * 32 + (l4 ^ ((rowA >> 1) & 3)) * 8]);
        }
        #pragma unroll
        for (int n = 0; n < 2; ++n) {
            const int rowB = wc * 32 + n * 16 + l15;
            b[n] = *reinterpret_cast<const bf16x8*>(&Bs[rowB * 32 + (l4 ^ ((rowB >> 1) & 3)) * 8]);
        }
        #pragma unroll
        for (int m = 0; m < 4; ++m)
            #pragma unroll
            for (int n = 0; n < 2; ++n)
                acc[m][n] = __builtin_amdgcn_mfma_f32_16x16x32_bf16(a[m], b[n], acc[m][n], 0, 0, 0);
    }

    // ---- epilogue: dist -> e = exp(-dist); write e (bf16); per-row partials ----
    const int row0 = bx * 128 + wr * 64;          // + m*16 + l4*4 + r
    const int col0 = by * 64 + wc * 32;           // + n*16 + l15

    float ps[2], pm[2];
    #pragma unroll
    for (int n = 0; n < 2; ++n) {
        const int c = col0 + n * 16 + l15;
        ps[n] = p_sq[c];
        pm[n] = p_sum[c];
    }
    const float dee = 1024.0f * EPS * EPS;

    #pragma unroll
    for (int m = 0; m < 4; ++m) {
        #pragma unroll
        for (int r = 0; r < 4; ++r) {
            const int row = row0 + m * 16 + l4 * 4 + r;
            const float qs = q_sq[row], qm = q_sum[row];
            float se = 0.0f, te = 0.0f, mx = 0.0f;
            #pragma unroll
            for (int n = 0; n < 2; ++n) {
                const float cross = acc[m][n][r];
                const float sq = qs + ps[n] - 2.0f * cross + 2.0f * EPS * (qm - pm[n]) + dee;
                const float dist = sqrtf(fmaxf(sq, 0.0f));
                const float e = __expf(-dist);
                e_out[(size_t)row * 1024 + (col0 + n * 16 + l15)] = f2bf(e);
                se += e;
                te += e * dist;
                mx = fmaxf(mx, e);
            }
            #pragma unroll
            for (int msk = 8; msk >= 1; msk >>= 1) {   // reduce over the 16-lane col group
                se += __shfl_xor(se, msk, 64);
                te += __shfl_xor(te, msk, 64);
                mx = fmaxf(mx, __shfl_xor(mx, msk, 64));
            }
            if (l15 == 0) {
                atomicAdd(&row_s[row], se);
                atomicAdd(&row_t[row], te);
                atomicMax(&row_m[row], __float_as_uint(mx));
            }
        }
    }
}

// ---------- kernel 3: merged finalize + normalize ----------
__global__ __launch_bounds__(256) void normfin_kernel(
    const unsigned short* __restrict__ e16,
    const float* __restrict__ row_s, const float* __restrict__ row_t,
    const unsigned int* __restrict__ row_m,
    float* __restrict__ post, float* __restrict__ c_out, float* __restrict__ h_out)
{
    const int row = blockIdx.x;
    const int tid = threadIdx.x;
    const float s   = row_s[row];
    const float inv = 1.0f / s;
    if (tid == 0) {
        c_out[row] = __uint_as_float(row_m[row]) * inv;
        h_out[row] = logf(s) + row_t[row] * inv;   // h = t/s + log s
    }
    const ushort4 ev = reinterpret_cast<const ushort4*>(e16 + (size_t)row * 1024)[tid];
    float4 o;
    o.x = bf2f(ev.x) * inv;
    o.y = bf2f(ev.y) * inv;
    o.z = bf2f(ev.z) * inv;
    o.w = bf2f(ev.w) * inv;
    reinterpret_cast<float4*>(post + (size_t)row * 1024)[tid] = o;
}

// ---------- launcher ----------
extern "C" void kernel_launch(void* const* d_in, const int* in_sizes, int n_in,
                              void* d_out, int out_size, void* d_ws, size_t ws_size,
                              hipStream_t stream) {
    const float* protos = (const float*)d_in[0];  // [1024,1024]
    const float* querys = (const float*)d_in[1];  // [8192,1024]

    float* out   = (float*)d_out;
    float* post  = out;                            // 8192*1024
    float* c_out = out + (size_t)8192 * 1024;      // 8192
    float* h_out = c_out + 8192;                   // 8192

    char* ws = (char*)d_ws;
    unsigned short* qb  = (unsigned short*)ws;  ws += (size_t)8192 * 1024 * 2;
    unsigned short* pb  = (unsigned short*)ws;  ws += (size_t)1024 * 1024 * 2;
    unsigned short* e16 = (unsigned short*)ws;  ws += (size_t)8192 * 1024 * 2;
    float* q_sq  = (float*)ws;  ws += 8192 * 4;
    float* q_sum = (float*)ws;  ws += 8192 * 4;
    float* p_sq  = (float*)ws;  ws += 1024 * 4;
    float* p_sum = (float*)ws;  ws += 1024 * 4;
    float* row_s = (float*)ws;  ws += 8192 * 4;
    float* row_t = (float*)ws;  ws += 8192 * 4;
    unsigned int* row_m = (unsigned int*)ws;  ws += 8192 * 4;

    // zero the atomic accumulators (row_s, row_t, row_m are contiguous)
    (void)hipMemsetAsync(row_s, 0, 3 * 8192 * sizeof(float), stream);

    prep_kernel<<<9216, 256, 0, stream>>>(protos, querys, pb, qb, p_sq, p_sum, q_sq, q_sum);
    gemm_exp_kernel<<<dim3(64, 16), 256, 0, stream>>>(qb, pb, q_sq, q_sum, p_sq, p_sum,
                                                      e16, row_s, row_t, row_m);
    normfin_kernel<<<8192, 256, 0, stream>>>(e16, row_s, row_t, row_m, post, c_out, h_out);
}

// Round 8
// 129.712 us; speedup vs baseline: 1.5515x; 1.0543x over previous
//
#include <hip/hip_runtime.h>
#include <hip/hip_bf16.h>

#define EPS 1e-6f

typedef float  f32x4  __attribute__((ext_vector_type(4)));
typedef __bf16 bf16x8 __attribute__((ext_vector_type(8)));

// ---------- helpers ----------
static __device__ __forceinline__ unsigned short f2bf(float f) {
    unsigned int x = __float_as_uint(f);
    unsigned int r = (x + 0x7FFFu + ((x >> 16) & 1u)) >> 16;   // RNE
    return (unsigned short)r;
}
static __device__ __forceinline__ float bf2f(unsigned short u) {
    return __uint_as_float((unsigned int)u << 16);
}

// ---------- kernel 1: row stats (fp32) + bf16 conversion, both matrices ----------
__global__ __launch_bounds__(256) void prep_kernel(
    const float* __restrict__ protos, const float* __restrict__ querys,
    unsigned short* __restrict__ pb, unsigned short* __restrict__ qb,
    float* __restrict__ p_sq, float* __restrict__ p_sum,
    float* __restrict__ q_sq, float* __restrict__ q_sum)
{
    const int b   = blockIdx.x;
    const int tid = threadIdx.x;
    const float* src; unsigned short* dst; float* rsq; float* rsum;
    if (b < 1024) {
        src = protos + (size_t)b * 1024; dst = pb + (size_t)b * 1024;
        rsq = p_sq + b; rsum = p_sum + b;
    } else {
        const int r = b - 1024;
        src = querys + (size_t)r * 1024; dst = qb + (size_t)r * 1024;
        rsq = q_sq + r; rsum = q_sum + r;
    }

    const float4 v = reinterpret_cast<const float4*>(src)[tid];
    float s  = v.x + v.y + v.z + v.w;
    float ss = v.x * v.x + v.y * v.y + v.z * v.z + v.w * v.w;

    ushort4 o;
    o.x = f2bf(v.x); o.y = f2bf(v.y); o.z = f2bf(v.z); o.w = f2bf(v.w);
    reinterpret_cast<ushort4*>(dst)[tid] = o;

    #pragma unroll
    for (int m = 32; m >= 1; m >>= 1) {
        s  += __shfl_xor(s, m, 64);
        ss += __shfl_xor(ss, m, 64);
    }
    __shared__ float red[8];
    const int wave = tid >> 6;
    if ((tid & 63) == 0) { red[wave] = s; red[4 + wave] = ss; }
    __syncthreads();
    if (tid == 0) {
        *rsum = red[0] + red[1] + red[2] + red[3];
        *rsq  = red[4] + red[5] + red[6] + red[7];
    }
}

// ---------- kernel 2: bf16 MFMA GEMM + dist/exp epilogue ----------
// Tile 128x128, BK=64, 256 threads = 4 waves (2x2), wave-tile 64x64 (4x4 frags,
// 2 k-slices per K-step). Single-buffered 32 KiB LDS; 16 barrier pairs total.
// Bank-conflict fix (rule #21, proven R7): linear global_load_lds dest + global
// source chunk pre-swizzled by (row&7) + matching XOR on ds_read chunk index.
// grid = 64x8 = 512 blocks = 2 blocks/CU; XCD swizzle gives each XCD P(2MB)+Q(2MB) in L2.
__global__ __launch_bounds__(256, 2) void gemm_exp_kernel(
    const unsigned short* __restrict__ qb,   // [8192][1024] bf16 bits
    const unsigned short* __restrict__ pb,   // [1024][1024] bf16 bits
    const float* __restrict__ q_sq, const float* __restrict__ q_sum,
    const float* __restrict__ p_sq, const float* __restrict__ p_sum,
    unsigned short* __restrict__ e_out,      // [8192][1024] bf16 un-normalized exp(-dist)
    float* __restrict__ row_s, float* __restrict__ row_t,
    unsigned int* __restrict__ row_m)
{
    __shared__ unsigned short As[128 * 64];  // 16 KiB, row = 8 chunks of 16 B
    __shared__ unsigned short Bs[128 * 64];  // 16 KiB

    const int tid  = threadIdx.x;
    const int lane = tid & 63;
    const int wave = tid >> 6;
    const int wr = wave >> 1, wc = wave & 1;
    const int l15 = lane & 15;
    const int l4  = lane >> 4;

    // XCD-aware bijective remap (512 blocks, 8 XCDs; 512%8==0)
    const int hwid  = blockIdx.x + blockIdx.y * 64;
    const int newid = (hwid & 7) * 64 + (hwid >> 3);
    const int bx = newid >> 3;    // row-block 0..63 (128 rows)
    const int by = newid & 7;     // col-block 0..7  (128 cols)

    f32x4 acc[4][4];
    #pragma unroll
    for (int m = 0; m < 4; ++m)
        #pragma unroll
        for (int n = 0; n < 4; ++n)
            acc[m][n] = (f32x4)0.0f;

    const size_t qbase = (size_t)(bx * 128) * 1024;
    const size_t pbase = (size_t)(by * 128) * 1024;

    for (int kk = 0; kk < 1024; kk += 64) {
        __syncthreads();
        // stage: 1024 chunks each of A and B; thread does 4 of each.
        // chunk lin -> LDS row = lin>>3, dest chunk cs = lin&7 (linear dest);
        // source chunk cg = cs ^ (row&7)  (involution; read applies same XOR)
        #pragma unroll
        for (int i = 0; i < 4; ++i) {
            const int lin = i * 256 + tid;
            const int row = lin >> 3;
            const int cg  = (lin & 7) ^ (row & 7);
            const unsigned short* ga = qb + qbase + (size_t)row * 1024 + kk + cg * 8;
            const unsigned short* gb = pb + pbase + (size_t)row * 1024 + kk + cg * 8;
            __builtin_amdgcn_global_load_lds((const __attribute__((address_space(1))) void*)ga,
                                             (__attribute__((address_space(3))) void*)(&As[lin * 8]), 16, 0, 0);
            __builtin_amdgcn_global_load_lds((const __attribute__((address_space(1))) void*)gb,
                                             (__attribute__((address_space(3))) void*)(&Bs[lin * 8]), 16, 0, 0);
        }
        __syncthreads();

        #pragma unroll
        for (int s = 0; s < 2; ++s) {
            bf16x8 a[4], b[4];
            #pragma unroll
            for (int m = 0; m < 4; ++m) {
                const int rowA = wr * 64 + m * 16 + l15;
                const int ca = (s * 4 + l4) ^ (rowA & 7);
                a[m] = *reinterpret_cast<const bf16x8*>(&As[rowA * 64 + ca * 8]);
            }
            #pragma unroll
            for (int n = 0; n < 4; ++n) {
                const int rowB = wc * 64 + n * 16 + l15;
                const int cb = (s * 4 + l4) ^ (rowB & 7);
                b[n] = *reinterpret_cast<const bf16x8*>(&Bs[rowB * 64 + cb * 8]);
            }
            #pragma unroll
            for (int m = 0; m < 4; ++m)
                #pragma unroll
                for (int n = 0; n < 4; ++n)
                    acc[m][n] = __builtin_amdgcn_mfma_f32_16x16x32_bf16(a[m], b[n], acc[m][n], 0, 0, 0);
        }
    }

    // ---- epilogue: dist -> e = exp(-dist); write e (bf16); per-row partials ----
    const int row0 = bx * 128 + wr * 64;          // + m*16 + l4*4 + r
    const int col0 = by * 128 + wc * 64;          // + n*16 + l15

    float ps[4], pm[4];
    #pragma unroll
    for (int n = 0; n < 4; ++n) {
        const int c = col0 + n * 16 + l15;
        ps[n] = p_sq[c];
        pm[n] = p_sum[c];
    }
    const float dee = 1024.0f * EPS * EPS;

    #pragma unroll
    for (int m = 0; m < 4; ++m) {
        #pragma unroll
        for (int r = 0; r < 4; ++r) {
            const int row = row0 + m * 16 + l4 * 4 + r;
            const float qs = q_sq[row], qm = q_sum[row];
            float se = 0.0f, te = 0.0f, mx = 0.0f;
            #pragma unroll
            for (int n = 0; n < 4; ++n) {
                const float cross = acc[m][n][r];
                const float sq = qs + ps[n] - 2.0f * cross + 2.0f * EPS * (qm - pm[n]) + dee;
                const float dist = sqrtf(fmaxf(sq, 0.0f));
                const float e = __expf(-dist);
                e_out[(size_t)row * 1024 + (col0 + n * 16 + l15)] = f2bf(e);
                se += e;
                te += e * dist;
                mx = fmaxf(mx, e);
            }
            #pragma unroll
            for (int msk = 8; msk >= 1; msk >>= 1) {
                se += __shfl_xor(se, msk, 64);
                te += __shfl_xor(te, msk, 64);
                mx = fmaxf(mx, __shfl_xor(mx, msk, 64));
            }
            if (l15 == 0) {
                atomicAdd(&row_s[row], se);
                atomicAdd(&row_t[row], te);
                atomicMax(&row_m[row], __float_as_uint(mx));
            }
        }
    }
}

// ---------- kernel 3: merged finalize + normalize ----------
__global__ __launch_bounds__(256) void normfin_kernel(
    const unsigned short* __restrict__ e16,
    const float* __restrict__ row_s, const float* __restrict__ row_t,
    const unsigned int* __restrict__ row_m,
    float* __restrict__ post, float* __restrict__ c_out, float* __restrict__ h_out)
{
    const int row = blockIdx.x;
    const int tid = threadIdx.x;
    const float s   = row_s[row];
    const float inv = 1.0f / s;
    if (tid == 0) {
        c_out[row] = __uint_as_float(row_m[row]) * inv;
        h_out[row] = logf(s) + row_t[row] * inv;   // h = t/s + log s
    }
    const ushort4 ev = reinterpret_cast<const ushort4*>(e16 + (size_t)row * 1024)[tid];
    float4 o;
    o.x = bf2f(ev.x) * inv;
    o.y = bf2f(ev.y) * inv;
    o.z = bf2f(ev.z) * inv;
    o.w = bf2f(ev.w) * inv;
    reinterpret_cast<float4*>(post + (size_t)row * 1024)[tid] = o;
}

// ---------- launcher ----------
extern "C" void kernel_launch(void* const* d_in, const int* in_sizes, int n_in,
                              void* d_out, int out_size, void* d_ws, size_t ws_size,
                              hipStream_t stream) {
    const float* protos = (const float*)d_in[0];  // [1024,1024]
    const float* querys = (const float*)d_in[1];  // [8192,1024]

    float* out   = (float*)d_out;
    float* post  = out;                            // 8192*1024
    float* c_out = out + (size_t)8192 * 1024;      // 8192
    float* h_out = c_out + 8192;                   // 8192

    char* ws = (char*)d_ws;
    unsigned short* qb  = (unsigned short*)ws;  ws += (size_t)8192 * 1024 * 2;
    unsigned short* pb  = (unsigned short*)ws;  ws += (size_t)1024 * 1024 * 2;
    unsigned short* e16 = (unsigned short*)ws;  ws += (size_t)8192 * 1024 * 2;
    float* q_sq  = (float*)ws;  ws += 8192 * 4;
    float* q_sum = (float*)ws;  ws += 8192 * 4;
    float* p_sq  = (float*)ws;  ws += 1024 * 4;
    float* p_sum = (float*)ws;  ws += 1024 * 4;
    float* row_s = (float*)ws;  ws += 8192 * 4;
    float* row_t = (float*)ws;  ws += 8192 * 4;
    unsigned int* row_m = (unsigned int*)ws;  ws += 8192 * 4;

    // zero the atomic accumulators (row_s, row_t, row_m are contiguous)
    (void)hipMemsetAsync(row_s, 0, 3 * 8192 * sizeof(float), stream);

    prep_kernel<<<9216, 256, 0, stream>>>(protos, querys, pb, qb, p_sq, p_sum, q_sq, q_sum);
    gemm_exp_kernel<<<dim3(64, 8), 256, 0, stream>>>(qb, pb, q_sq, q_sum, p_sq, p_sum,
                                                     e16, row_s, row_t, row_m);
    normfin_kernel<<<8192, 256, 0, stream>>>(e16, row_s, row_t, row_m, post, c_out, h_out);
}